// Round 4
// baseline (466.868 us; speedup 1.0000x reference)
//
#include <hip/hip_runtime.h>

// Problem constants (match reference)
#define N_NODES 50000
#define N_EDGES 800000
#define F_IN 128
#define H1 100
#define H2 200
#define F_OUT 16

// ---------------- CSR build ----------------

__global__ void count_kernel(const int* __restrict__ col, int* __restrict__ cnt, int n_edges) {
    int e = blockIdx.x * blockDim.x + threadIdx.x;
    if (e < n_edges) atomicAdd(&cnt[col[e]], 1);
}

__global__ void dis_kernel(const int* __restrict__ cnt, float* __restrict__ dis, int n) {
    int i = blockIdx.x * blockDim.x + threadIdx.x;
    if (i < n) dis[i] = rsqrtf((float)cnt[i] + 1.0f);  // +1 = self loop
}

// Single-block exclusive scan, int4-strided.
__global__ void scan_kernel(const int* __restrict__ cnt, int* __restrict__ offs, int n4, int n) {
    __shared__ int wsum[16];
    int tid = threadIdx.x, lane = tid & 63, wid = tid >> 6;
    int carry = 0;
    const int4* c4 = (const int4*)cnt;
    int4* o4 = (int4*)offs;
    for (int base = 0; base < n4; base += 1024) {
        int i = base + tid;
        int4 v = (i < n4) ? c4[i] : make_int4(0, 0, 0, 0);
        int tsum = v.x + v.y + v.z + v.w;
        int s = tsum;
#pragma unroll
        for (int d = 1; d < 64; d <<= 1) {
            int t = __shfl_up(s, d);
            if (lane >= d) s += t;
        }
        if (lane == 63) wsum[wid] = s;
        __syncthreads();
        if (wid == 0) {
            int ws = (lane < 16) ? wsum[lane] : 0;
#pragma unroll
            for (int d = 1; d < 16; d <<= 1) {
                int t = __shfl_up(ws, d);
                if (lane >= d) ws += t;
            }
            if (lane < 16) wsum[lane] = ws;  // inclusive wave-sums
        }
        __syncthreads();
        int wbase = wid ? wsum[wid - 1] : 0;
        int total = wsum[15];
        int excl = carry + wbase + (s - tsum);
        if (i < n4) o4[i] = make_int4(excl, excl + v.x, excl + v.x + v.y, excl + v.x + v.y + v.z);
        carry += total;
        __syncthreads();  // protect wsum before next chunk overwrites
    }
    if (tid == 0) offs[n] = carry;
}

__global__ void fill_kernel(const int* __restrict__ row, const int* __restrict__ col,
                            const int* __restrict__ offs, int* __restrict__ cursor,
                            int* __restrict__ csr, int n_edges) {
    int e = blockIdx.x * blockDim.x + threadIdx.x;
    if (e < n_edges) {
        int c = col[e];
        int p = offs[c] + atomicAdd(&cursor[c], 1);
        csr[p] = row[e];
    }
}

// ---------------- Row-blocked GEMM with dis-scale epilogue ----------------
// out[n][c] = dis[n] * sum_k in[n][k]*W[k][c]
// One block = RPB rows x all NO cols. Row addresses are threadIdx-independent
// -> compiler scalarizes in[] loads to s_load with immediate offsets; each
// coalesced W vector-load feeds RPB independent FMAs (latency hiding via ILP).
// Requires grid*RPB == n_rows (50000 = 16*3125, no tail).

template <int K, int NO, int RPB>
__global__ void gemm_rowblk_kernel(const float* __restrict__ in, const float* __restrict__ W,
                                   const float* __restrict__ dis, float* __restrict__ out) {
    int c = threadIdx.x;
    if (c >= NO) return;
    int n0 = blockIdx.x * RPB;
    const float* inb = in + (size_t)n0 * K;
    float acc[RPB];
#pragma unroll
    for (int r = 0; r < RPB; ++r) acc[r] = 0.f;
    const float* Wc = W + c;
#pragma unroll 2
    for (int k = 0; k < K; ++k) {
        float w = Wc[k * NO];
#pragma unroll
        for (int r = 0; r < RPB; ++r) acc[r] = fmaf(inb[r * K + k], w, acc[r]);
    }
#pragma unroll
    for (int r = 0; r < RPB; ++r) out[(size_t)(n0 + r) * NO + c] = acc[r] * dis[n0 + r];
}

// ---------------- Aggregation over 100-wide rows (float2, one wave per node) ----------------
// acc[n] = y[n] + sum_{src in in(n)} y[src]
// BIAS_RELU=true  : out[n] = relu(dis[n]*acc + b) * dis[n]   (layer-1 output, pre-scaled for layer-2 gather)
// BIAS_RELU=false : out[n] = dis[n]*acc                      (layer-2 aggregated input)

template <bool BIAS_RELU>
__global__ void agg100_kernel(const float* __restrict__ y, const int* __restrict__ offs,
                              const int* __restrict__ csr, const float* __restrict__ dis,
                              const float* __restrict__ bias, float* __restrict__ out, int n_nodes) {
    int wave = threadIdx.x >> 6, lane = threadIdx.x & 63;
    int n = blockIdx.x * 4 + wave;
    if (n >= n_nodes) return;
    const float2* Y = (const float2*)y;
    bool act = lane < 50;
    float ax = 0.f, ay = 0.f;
    if (act) {
        float2 v = Y[n * 50 + lane];  // self-loop term
        ax = v.x; ay = v.y;
    }
    int e0 = offs[n], e1 = offs[n + 1];
    for (int eb = e0; eb < e1; eb += 64) {
        int cdeg = min(e1 - eb, 64);
        int my = (lane < cdeg) ? csr[eb + lane] : 0;  // coalesced batch of edge srcs
        int i = 0;
        for (; i + 4 <= cdeg; i += 4) {
            int s0 = __shfl(my, i), s1 = __shfl(my, i + 1);
            int s2 = __shfl(my, i + 2), s3 = __shfl(my, i + 3);
            if (act) {
                float2 v0 = Y[s0 * 50 + lane];
                float2 v1 = Y[s1 * 50 + lane];
                float2 v2 = Y[s2 * 50 + lane];
                float2 v3 = Y[s3 * 50 + lane];
                ax += (v0.x + v1.x) + (v2.x + v3.x);
                ay += (v0.y + v1.y) + (v2.y + v3.y);
            }
        }
        for (; i < cdeg; ++i) {
            int s = __shfl(my, i);
            if (act) {
                float2 v = Y[s * 50 + lane];
                ax += v.x; ay += v.y;
            }
        }
    }
    if (act) {
        float d = dis[n];
        float ox, oy;
        if (BIAS_RELU) {
            int f = lane * 2;
            ox = fmaxf(fmaf(ax, d, bias[f]), 0.f) * d;
            oy = fmaxf(fmaf(ay, d, bias[f + 1]), 0.f) * d;
        } else {
            ox = ax * d;
            oy = ay * d;
        }
        ((float2*)out)[n * 50 + lane] = make_float2(ox, oy);
    }
}

// ---------------- Fused layer-2 GEMM + bias + relu + final FC ----------------
// Block = 16 rows. Phase 1 (threads 0..199): h2s[r][:] = relu(g2[n0+r]@W2 + b2)
// with 16-row register blocking (scalarized g2 loads). Phase 2 (all 256):
// one (row,col) output each: out[n0+r][l] = h2s[r][:]@Wfc[:,l] + bfc[l].

__global__ void gemm2_fc_kernel(const float* __restrict__ g2, const float* __restrict__ W2,
                                const float* __restrict__ b2, const float* __restrict__ Wfc,
                                const float* __restrict__ bfc, float* __restrict__ out) {
    __shared__ float h2s[16][204];  // pad 200->204: 16B-aligned float4, bank-stride 12 (<=2-way)
    int t = threadIdx.x;
    int n0 = blockIdx.x * 16;
    if (t < H2) {
        const float* gb = g2 + (size_t)n0 * H1;
        float acc[16];
#pragma unroll
        for (int r = 0; r < 16; ++r) acc[r] = 0.f;
        const float* Wc = W2 + t;
#pragma unroll 2
        for (int k = 0; k < H1; ++k) {
            float w = Wc[k * H2];
#pragma unroll
            for (int r = 0; r < 16; ++r) acc[r] = fmaf(gb[r * H1 + k], w, acc[r]);
        }
        float bb = b2[t];
#pragma unroll
        for (int r = 0; r < 16; ++r) h2s[r][t] = fmaxf(acc[r] + bb, 0.f);
    }
    __syncthreads();
    int r = t >> 4, l = t & 15;
    float a = bfc[l];
    const float* Wl = Wfc + l;
#pragma unroll 4
    for (int k = 0; k < H2; k += 4) {
        float4 h = *reinterpret_cast<const float4*>(&h2s[r][k]);
        a = fmaf(h.x, Wl[k * F_OUT], a);
        a = fmaf(h.y, Wl[(k + 1) * F_OUT], a);
        a = fmaf(h.z, Wl[(k + 2) * F_OUT], a);
        a = fmaf(h.w, Wl[(k + 3) * F_OUT], a);
    }
    out[(size_t)(n0 + r) * F_OUT + l] = a;
}

// ---------------- Launch ----------------

extern "C" void kernel_launch(void* const* d_in, const int* in_sizes, int n_in,
                              void* d_out, int out_size, void* d_ws, size_t ws_size,
                              hipStream_t stream) {
    const float* x   = (const float*)d_in[0];
    const int*   ei  = (const int*)d_in[1];
    const float* W1  = (const float*)d_in[2];
    const float* b1  = (const float*)d_in[3];
    const float* W2  = (const float*)d_in[4];
    const float* b2  = (const float*)d_in[5];
    const float* Wfc = (const float*)d_in[6];
    const float* bfc = (const float*)d_in[7];
    float* out = (float*)d_out;

    const int N = N_NODES, E = N_EDGES;
    const int* row = ei;
    const int* col = ei + E;

    // Workspace layout (16B-aligned sections)
    char* ws = (char*)d_ws;
    int*   cnt    = (int*)ws;    ws += (size_t)N * 4;
    int*   cursor = (int*)ws;    ws += (size_t)N * 4;
    float* dis    = (float*)ws;  ws += (size_t)N * 4;
    int*   offs   = (int*)ws;    ws += (size_t)(N + 4) * 4;  // padded -> keeps 16B align
    int*   csr    = (int*)ws;    ws += (size_t)E * 4;
    float* y1     = (float*)ws;  ws += (size_t)N * H1 * 4;   // 20 MB
    float* h1s    = (float*)ws;  ws += (size_t)N * H1 * 4;   // 20 MB
    float* g2     = (float*)ws;  ws += (size_t)N * H1 * 4;   // 20 MB

    hipMemsetAsync(cnt, 0, (size_t)N * 2 * 4, stream);  // cnt + cursor (contiguous)

    count_kernel<<<(E + 255) / 256, 256, 0, stream>>>(col, cnt, E);
    dis_kernel<<<(N + 255) / 256, 256, 0, stream>>>(cnt, dis, N);
    scan_kernel<<<1, 1024, 0, stream>>>(cnt, offs, N / 4, N);
    fill_kernel<<<(E + 255) / 256, 256, 0, stream>>>(row, col, offs, cursor, csr, E);

    // Layer 1 (GEMM first: thin side is H1=100 < F_IN=128):
    // y1 = (x@W1)*dis ; h1s = relu(dis*agg(y1) + b1) * dis
    gemm_rowblk_kernel<F_IN, H1, 16><<<N / 16, 128, 0, stream>>>(x, W1, dis, y1);
    agg100_kernel<true><<<N / 4, 256, 0, stream>>>(y1, offs, csr, dis, b1, h1s, N);

    // Layer 2 (aggregate first: thin side is H1=100 < H2=200):
    // g2 = dis*agg(h1s) ; out = relu(g2@W2 + b2) @ Wfc + bfc
    agg100_kernel<false><<<N / 4, 256, 0, stream>>>(h1s, offs, csr, dis, (const float*)nullptr, g2, N);
    gemm2_fc_kernel<<<N / 16, 256, 0, stream>>>(g2, W2, b2, Wfc, bfc, out);
}

// Round 5
// 380.736 us; speedup vs baseline: 1.2262x; 1.2262x over previous
//
#include <hip/hip_runtime.h>

// Problem constants (match reference)
#define N_NODES 50000
#define N_EDGES 800000
#define F_IN 128
#define H1 100
#define H2 200
#define F_OUT 16

// ---------------- small float4 helpers ----------------
__device__ __forceinline__ float4 f4fma(float s, float4 v, float4 a) {
    a.x = fmaf(s, v.x, a.x); a.y = fmaf(s, v.y, a.y);
    a.z = fmaf(s, v.z, a.z); a.w = fmaf(s, v.w, a.w);
    return a;
}
__device__ __forceinline__ float4 f4scale(float4 v, float s) {
    return make_float4(v.x * s, v.y * s, v.z * s, v.w * s);
}
__device__ __forceinline__ float4 f4relu_add(float4 v, float4 b) {
    return make_float4(fmaxf(v.x + b.x, 0.f), fmaxf(v.y + b.y, 0.f),
                       fmaxf(v.z + b.z, 0.f), fmaxf(v.w + b.w, 0.f));
}

// ---------------- CSR build ----------------

__global__ void count_kernel(const int* __restrict__ col, int* __restrict__ cnt, int n_edges) {
    int e = blockIdx.x * blockDim.x + threadIdx.x;
    if (e < n_edges) atomicAdd(&cnt[col[e]], 1);
}

__global__ void dis_kernel(const int* __restrict__ cnt, float* __restrict__ dis, int n) {
    int i = blockIdx.x * blockDim.x + threadIdx.x;
    if (i < n) dis[i] = rsqrtf((float)cnt[i] + 1.0f);  // +1 = self loop
}

// Single-block exclusive scan, int4-strided.
__global__ void scan_kernel(const int* __restrict__ cnt, int* __restrict__ offs, int n4, int n) {
    __shared__ int wsum[16];
    int tid = threadIdx.x, lane = tid & 63, wid = tid >> 6;
    int carry = 0;
    const int4* c4 = (const int4*)cnt;
    int4* o4 = (int4*)offs;
    for (int base = 0; base < n4; base += 1024) {
        int i = base + tid;
        int4 v = (i < n4) ? c4[i] : make_int4(0, 0, 0, 0);
        int tsum = v.x + v.y + v.z + v.w;
        int s = tsum;
#pragma unroll
        for (int d = 1; d < 64; d <<= 1) {
            int t = __shfl_up(s, d);
            if (lane >= d) s += t;
        }
        if (lane == 63) wsum[wid] = s;
        __syncthreads();
        if (wid == 0) {
            int ws = (lane < 16) ? wsum[lane] : 0;
#pragma unroll
            for (int d = 1; d < 16; d <<= 1) {
                int t = __shfl_up(ws, d);
                if (lane >= d) ws += t;
            }
            if (lane < 16) wsum[lane] = ws;  // inclusive wave-sums
        }
        __syncthreads();
        int wbase = wid ? wsum[wid - 1] : 0;
        int total = wsum[15];
        int excl = carry + wbase + (s - tsum);
        if (i < n4) o4[i] = make_int4(excl, excl + v.x, excl + v.x + v.y, excl + v.x + v.y + v.z);
        carry += total;
        __syncthreads();  // protect wsum before next chunk overwrites
    }
    if (tid == 0) offs[n] = carry;
}

__global__ void fill_kernel(const int* __restrict__ row, const int* __restrict__ col,
                            const int* __restrict__ offs, int* __restrict__ cursor,
                            int* __restrict__ csr, int n_edges) {
    int e = blockIdx.x * blockDim.x + threadIdx.x;
    if (e < n_edges) {
        int c = col[e];
        int p = offs[c] + atomicAdd(&cursor[c], 1);
        csr[p] = row[e];
    }
}

// ---------------- LDS-tiled GEMM ----------------
// C[n][c] = epilogue( sum_k A[n][k] * W[k][c] ),  c in [col_off, col_off+100)
// BM=80 rows/block (50000 = 625*80, no tail), 256 threads = 16(tx) x 16(ty),
// per-thread tile TM=5 rows x TN=8 cols (virtual 128 cols, guarded at <100).
// A-tile row-major in LDS (pitch BK+4); compute reads are 4-distinct-address
// broadcasts (conflict-free). B-tile pitch 104, read as 2x ds_read_b128.
// EPI=0: out[n][c] = acc * dis[n]            (layer-1: y1, pre-scaled)
// EPI=1: out[n][col_off+c] = relu(acc + b[col_off+c])   (layer-2: h2)

template <int K, int BK, int LDW, int EPI>
__global__ void gemm_tiled_kernel(const float* __restrict__ A, const float* __restrict__ W,
                                  const float* __restrict__ db, float* __restrict__ out,
                                  int ldo) {
    constexpr int BM = 80, TM = 5;
    constexpr int APITCH = BK + 4;     // 36 or 24: float4-aligned, conflict-free A reads
    constexpr int BPITCH = 104;        // 100 + 4 zero pad
    constexpr int AQ = BK / 4;         // float4s per A row-chunk
    __shared__ float As[BM * APITCH];
    __shared__ float Bs[BK * BPITCH];

    int tid = threadIdx.x;
    int tx = tid & 15, ty = tid >> 4;
    int n0 = blockIdx.x * BM;
    int col_off = blockIdx.y * 100;

    float4 accL[TM], accH[TM];
#pragma unroll
    for (int r = 0; r < TM; ++r) {
        accL[r] = make_float4(0.f, 0.f, 0.f, 0.f);
        accH[r] = make_float4(0.f, 0.f, 0.f, 0.f);
    }

    for (int kc = 0; kc < K; kc += BK) {
        __syncthreads();  // previous compute done before overwrite (no-op first iter)
        // stage A: BM rows x AQ float4 (coalesced)
        for (int i = tid; i < BM * AQ; i += 256) {
            int row = i / AQ, q = i - row * AQ;
            float4 v = *(const float4*)&A[(size_t)(n0 + row) * K + kc + q * 4];
            *(float4*)&As[row * APITCH + q * 4] = v;
        }
        // stage B: BK rows x 52 float2 (cols >=100 zero-filled)
        for (int i = tid; i < BK * 52; i += 256) {
            int row = i / 52, c2 = i - row * 52;
            float2 v = (c2 < 50)
                ? *(const float2*)&W[(size_t)(kc + row) * LDW + col_off + c2 * 2]
                : make_float2(0.f, 0.f);
            *(float2*)&Bs[row * BPITCH + c2 * 2] = v;
        }
        __syncthreads();
#pragma unroll 4
        for (int kk = 0; kk < BK; ++kk) {
            float4 bA = *(const float4*)&Bs[kk * BPITCH + tx * 8];
            float4 bB = *(const float4*)&Bs[kk * BPITCH + tx * 8 + 4];
            float a[TM];
#pragma unroll
            for (int r = 0; r < TM; ++r) a[r] = As[(ty * TM + r) * APITCH + kk];
#pragma unroll
            for (int r = 0; r < TM; ++r) {
                accL[r] = f4fma(a[r], bA, accL[r]);
                accH[r] = f4fma(a[r], bB, accH[r]);
            }
        }
    }

    int c0 = tx * 8;
    bool stL = (c0 < 100), stH = (c0 + 4 < 100);
    if (EPI == 0) {
#pragma unroll
        for (int r = 0; r < TM; ++r) {
            int n = n0 + ty * TM + r;
            float d = db[n];
            if (stL) *(float4*)&out[(size_t)n * ldo + c0] = f4scale(accL[r], d);
            if (stH) *(float4*)&out[(size_t)n * ldo + c0 + 4] = f4scale(accH[r], d);
        }
    } else {
        float4 bb0 = make_float4(0.f, 0.f, 0.f, 0.f), bb1 = bb0;
        if (stL) bb0 = *(const float4*)&db[col_off + c0];
        if (stH) bb1 = *(const float4*)&db[col_off + c0 + 4];
#pragma unroll
        for (int r = 0; r < TM; ++r) {
            int n = n0 + ty * TM + r;
            if (stL) *(float4*)&out[(size_t)n * ldo + col_off + c0] = f4relu_add(accL[r], bb0);
            if (stH) *(float4*)&out[(size_t)n * ldo + col_off + c0 + 4] = f4relu_add(accH[r], bb1);
        }
    }
}

// ---------------- Aggregation over 100-wide rows (float2, one wave per node) ----------------
// acc[n] = y[n] + sum_{src in in(n)} y[src]
// BIAS_RELU=true  : out[n] = relu(dis[n]*acc + b) * dis[n]   (layer-1 output, pre-scaled for layer-2 gather)
// BIAS_RELU=false : out[n] = dis[n]*acc                      (layer-2 aggregated input)

template <bool BIAS_RELU>
__global__ void agg100_kernel(const float* __restrict__ y, const int* __restrict__ offs,
                              const int* __restrict__ csr, const float* __restrict__ dis,
                              const float* __restrict__ bias, float* __restrict__ out, int n_nodes) {
    int wave = threadIdx.x >> 6, lane = threadIdx.x & 63;
    int n = blockIdx.x * 4 + wave;
    if (n >= n_nodes) return;
    const float2* Y = (const float2*)y;
    bool act = lane < 50;
    float ax = 0.f, ay = 0.f;
    if (act) {
        float2 v = Y[n * 50 + lane];  // self-loop term
        ax = v.x; ay = v.y;
    }
    int e0 = offs[n], e1 = offs[n + 1];
    for (int eb = e0; eb < e1; eb += 64) {
        int cdeg = min(e1 - eb, 64);
        int my = (lane < cdeg) ? csr[eb + lane] : 0;  // coalesced batch of edge srcs
        int i = 0;
        for (; i + 4 <= cdeg; i += 4) {
            int s0 = __shfl(my, i), s1 = __shfl(my, i + 1);
            int s2 = __shfl(my, i + 2), s3 = __shfl(my, i + 3);
            if (act) {
                float2 v0 = Y[s0 * 50 + lane];
                float2 v1 = Y[s1 * 50 + lane];
                float2 v2 = Y[s2 * 50 + lane];
                float2 v3 = Y[s3 * 50 + lane];
                ax += (v0.x + v1.x) + (v2.x + v3.x);
                ay += (v0.y + v1.y) + (v2.y + v3.y);
            }
        }
        for (; i < cdeg; ++i) {
            int s = __shfl(my, i);
            if (act) {
                float2 v = Y[s * 50 + lane];
                ax += v.x; ay += v.y;
            }
        }
    }
    if (act) {
        float d = dis[n];
        float ox, oy;
        if (BIAS_RELU) {
            int f = lane * 2;
            ox = fmaxf(fmaf(ax, d, bias[f]), 0.f) * d;
            oy = fmaxf(fmaf(ay, d, bias[f + 1]), 0.f) * d;
        } else {
            ox = ax * d;
            oy = ay * d;
        }
        ((float2*)out)[n * 50 + lane] = make_float2(ox, oy);
    }
}

// ---------------- Final FC: out[n][c] = h[n]@Wfc + bfc, thread handles (n, 4 cols) ----------------

__global__ void fc_kernel(const float* __restrict__ h, const float* __restrict__ W,
                          const float* __restrict__ b, float* __restrict__ out, int n_rows) {
    int idx = blockIdx.x * blockDim.x + threadIdx.x;
    int n = idx >> 2;
    int cg = (idx & 3) * 4;
    if (n >= n_rows) return;
    float a0 = 0.f, a1 = 0.f, a2 = 0.f, a3 = 0.f;
    const float* hr = h + (size_t)n * H2;
#pragma unroll 2
    for (int k0 = 0; k0 < H2; k0 += 4) {
        float4 xv = *reinterpret_cast<const float4*>(hr + k0);
        float xs[4] = {xv.x, xv.y, xv.z, xv.w};
#pragma unroll
        for (int kk = 0; kk < 4; ++kk) {
            float4 wv = *reinterpret_cast<const float4*>(W + (k0 + kk) * F_OUT + cg);
            a0 = fmaf(xs[kk], wv.x, a0);
            a1 = fmaf(xs[kk], wv.y, a1);
            a2 = fmaf(xs[kk], wv.z, a2);
            a3 = fmaf(xs[kk], wv.w, a3);
        }
    }
    float4 bv = *reinterpret_cast<const float4*>(b + cg);
    float4 o = {a0 + bv.x, a1 + bv.y, a2 + bv.z, a3 + bv.w};
    *reinterpret_cast<float4*>(out + (size_t)n * F_OUT + cg) = o;
}

// ---------------- Launch ----------------

extern "C" void kernel_launch(void* const* d_in, const int* in_sizes, int n_in,
                              void* d_out, int out_size, void* d_ws, size_t ws_size,
                              hipStream_t stream) {
    const float* x   = (const float*)d_in[0];
    const int*   ei  = (const int*)d_in[1];
    const float* W1  = (const float*)d_in[2];
    const float* b1  = (const float*)d_in[3];
    const float* W2  = (const float*)d_in[4];
    const float* b2  = (const float*)d_in[5];
    const float* Wfc = (const float*)d_in[6];
    const float* bfc = (const float*)d_in[7];
    float* out = (float*)d_out;

    const int N = N_NODES, E = N_EDGES;
    const int* row = ei;
    const int* col = ei + E;

    // Workspace layout (all sections 16B-aligned)
    char* ws = (char*)d_ws;
    int*   cnt    = (int*)ws;    ws += (size_t)N * 4;
    int*   cursor = (int*)ws;    ws += (size_t)N * 4;
    float* dis    = (float*)ws;  ws += (size_t)N * 4;
    int*   offs   = (int*)ws;    ws += (size_t)(N + 4) * 4;  // padded -> keeps 16B align
    int*   csr    = (int*)ws;    ws += (size_t)E * 4;
    float* y1     = (float*)ws;  ws += (size_t)N * H1 * 4;   // 20 MB
    float* h1s    = (float*)ws;  ws += (size_t)N * H1 * 4;   // 20 MB
    float* g2     = (float*)ws;  ws += (size_t)N * H1 * 4;   // 20 MB
    float* h2     = y1;  // overlay: y1+h1s dead after agg2; h2 = N*H2 = 40 MB spans both

    hipMemsetAsync(cnt, 0, (size_t)N * 2 * 4, stream);  // cnt + cursor (contiguous)

    count_kernel<<<(E + 255) / 256, 256, 0, stream>>>(col, cnt, E);
    dis_kernel<<<(N + 255) / 256, 256, 0, stream>>>(cnt, dis, N);
    scan_kernel<<<1, 1024, 0, stream>>>(cnt, offs, N / 4, N);
    fill_kernel<<<(E + 255) / 256, 256, 0, stream>>>(row, col, offs, cursor, csr, E);

    // Layer 1 (GEMM first: thin side is H1=100 < F_IN=128):
    // y1 = (x@W1)*dis ; h1s = relu(dis*agg(y1) + b1) * dis
    gemm_tiled_kernel<F_IN, 32, H1, 0><<<dim3(N / 80, 1), 256, 0, stream>>>(x, W1, dis, y1, H1);
    agg100_kernel<true><<<N / 4, 256, 0, stream>>>(y1, offs, csr, dis, b1, h1s, N);

    // Layer 2 (aggregate first: thin side is H1=100 < H2=200):
    // g2 = dis*agg(h1s) ; h2 = relu(g2@W2 + b2) ; out = h2@Wfc + bfc
    agg100_kernel<false><<<N / 4, 256, 0, stream>>>(h1s, offs, csr, dis, (const float*)nullptr, g2, N);
    gemm_tiled_kernel<H1, 20, H2, 1><<<dim3(N / 80, 2), 256, 0, stream>>>(g2, W2, b2, h2, H2);
    fc_kernel<<<(N * 4 + 255) / 256, 256, 0, stream>>>(h2, Wfc, bfc, out, N);
}

// Round 6
// 336.440 us; speedup vs baseline: 1.3877x; 1.1317x over previous
//
#include <hip/hip_runtime.h>
#include <hip/hip_fp16.h>

// Problem constants (match reference)
#define N_NODES 50000
#define N_EDGES 800000
#define F_IN 128
#define H1 100
#define H2 200
#define F_OUT 16

// ---------------- small float4 helpers ----------------
__device__ __forceinline__ float4 f4fma(float s, float4 v, float4 a) {
    a.x = fmaf(s, v.x, a.x); a.y = fmaf(s, v.y, a.y);
    a.z = fmaf(s, v.z, a.z); a.w = fmaf(s, v.w, a.w);
    return a;
}

// ---------------- CSR build ----------------

__global__ void count_kernel(const int* __restrict__ col, int* __restrict__ cnt, int n_edges) {
    int e = blockIdx.x * blockDim.x + threadIdx.x;
    if (e < n_edges) atomicAdd(&cnt[col[e]], 1);
}

__global__ void dis_kernel(const int* __restrict__ cnt, float* __restrict__ dis, int n) {
    int i = blockIdx.x * blockDim.x + threadIdx.x;
    if (i < n) dis[i] = rsqrtf((float)cnt[i] + 1.0f);  // +1 = self loop
}

// ---- 3-phase parallel exclusive scan over N ints (N/4 int4s) ----
// Phase 1: each block scans 1024 int4s (4096 ints), writes local-exclusive
// partials + its block total. Phase 2: 1 wave scans block totals. Phase 3: add.

__global__ void scan_block_kernel(const int* __restrict__ cnt, int* __restrict__ offs,
                                  int* __restrict__ bsum, int n4) {
    __shared__ int wsum[16];
    int tid = threadIdx.x, lane = tid & 63, wid = tid >> 6;
    const int4* c4 = (const int4*)cnt;
    int4* o4 = (int4*)offs;
    int i = blockIdx.x * 1024 + tid;
    int4 v = (i < n4) ? c4[i] : make_int4(0, 0, 0, 0);
    int tsum = v.x + v.y + v.z + v.w;
    int s = tsum;
#pragma unroll
    for (int d = 1; d < 64; d <<= 1) {
        int t = __shfl_up(s, d);
        if (lane >= d) s += t;
    }
    if (lane == 63) wsum[wid] = s;
    __syncthreads();
    if (wid == 0) {
        int ws = (lane < 16) ? wsum[lane] : 0;
#pragma unroll
        for (int d = 1; d < 16; d <<= 1) {
            int t = __shfl_up(ws, d);
            if (lane >= d) ws += t;
        }
        if (lane < 16) wsum[lane] = ws;  // inclusive wave-sums
    }
    __syncthreads();
    int wbase = wid ? wsum[wid - 1] : 0;
    int excl = wbase + (s - tsum);  // block-local exclusive
    if (i < n4) o4[i] = make_int4(excl, excl + v.x, excl + v.x + v.y, excl + v.x + v.y + v.z);
    if (tid == 0) bsum[blockIdx.x] = wsum[15];
}

__global__ void scan_bsum_kernel(const int* __restrict__ bsum, int* __restrict__ bbase, int nb) {
    int lane = threadIdx.x;  // 64 threads, nb <= 63
    int v = (lane < nb) ? bsum[lane] : 0;
    int s = v;
#pragma unroll
    for (int d = 1; d < 64; d <<= 1) {
        int t = __shfl_up(s, d);
        if (lane >= d) s += t;
    }
    if (lane < nb) bbase[lane] = s - v;  // exclusive
    if (lane == nb - 1) bbase[nb] = s;   // grand total
}

__global__ void scan_add_kernel(int* __restrict__ offs, const int* __restrict__ bbase,
                                int n4, int n, int nb) {
    int i = blockIdx.x * blockDim.x + threadIdx.x;
    int4* o4 = (int4*)offs;
    if (i < n4) {
        int base = bbase[i >> 10];
        int4 v = o4[i];
        v.x += base; v.y += base; v.z += base; v.w += base;
        o4[i] = v;
    }
    if (i == 0) offs[n] = bbase[nb];
}

__global__ void fill_kernel(const int* __restrict__ row, const int* __restrict__ col,
                            const int* __restrict__ offs, int* __restrict__ cursor,
                            int* __restrict__ csr, int n_edges) {
    int e = blockIdx.x * blockDim.x + threadIdx.x;
    if (e < n_edges) {
        int c = col[e];
        int p = offs[c] + atomicAdd(&cursor[c], 1);
        csr[p] = row[e];
    }
}

// ---------------- LDS-tiled GEMM, fp16 output (pitch 104 halves) ----------------
// acc[n][c] = sum_k A[n][k] * W[k][c],  c in [col_off, col_off+100)
// BM=80 rows/block, 256 threads = 16(tx) x 16(ty), thread tile 5 rows x 8 cols.
// EPI=0: o[n][c] = (half) acc * db[n]                      (y1s, dis-pre-scaled)
// EPI=1: o[plane(by)][n][c] = (half) relu(acc + db[coloff+c])  (h2 col-planes)

template <int K, int BK, int LDW, int EPI>
__global__ void gemm_tiled_kernel(const float* __restrict__ A, const float* __restrict__ W,
                                  const float* __restrict__ db, void* __restrict__ out,
                                  size_t planeH) {
    constexpr int BM = 80, TM = 5;
    constexpr int APITCH = BK + 4;
    constexpr int BPITCH = 104;
    constexpr int AQ = BK / 4;
    __shared__ float As[BM * APITCH];
    __shared__ float Bs[BK * BPITCH];

    int tid = threadIdx.x;
    int tx = tid & 15, ty = tid >> 4;
    int n0 = blockIdx.x * BM;
    int col_off = blockIdx.y * 100;

    float4 accL[TM], accH[TM];
#pragma unroll
    for (int r = 0; r < TM; ++r) {
        accL[r] = make_float4(0.f, 0.f, 0.f, 0.f);
        accH[r] = make_float4(0.f, 0.f, 0.f, 0.f);
    }

    for (int kc = 0; kc < K; kc += BK) {
        __syncthreads();
        for (int i = tid; i < BM * AQ; i += 256) {
            int row = i / AQ, q = i - row * AQ;
            float4 v = *(const float4*)&A[(size_t)(n0 + row) * K + kc + q * 4];
            *(float4*)&As[row * APITCH + q * 4] = v;
        }
        for (int i = tid; i < BK * 52; i += 256) {
            int row = i / 52, c2 = i - row * 52;
            float2 v = (c2 < 50)
                ? *(const float2*)&W[(size_t)(kc + row) * LDW + col_off + c2 * 2]
                : make_float2(0.f, 0.f);
            *(float2*)&Bs[row * BPITCH + c2 * 2] = v;
        }
        __syncthreads();
#pragma unroll 4
        for (int kk = 0; kk < BK; ++kk) {
            float4 bA = *(const float4*)&Bs[kk * BPITCH + tx * 8];
            float4 bB = *(const float4*)&Bs[kk * BPITCH + tx * 8 + 4];
            float a[TM];
#pragma unroll
            for (int r = 0; r < TM; ++r) a[r] = As[(ty * TM + r) * APITCH + kk];
#pragma unroll
            for (int r = 0; r < TM; ++r) {
                accL[r] = f4fma(a[r], bA, accL[r]);
                accH[r] = f4fma(a[r], bB, accH[r]);
            }
        }
    }

    int c0 = tx * 8;
    bool stL = (c0 < 100), stH = (c0 + 4 < 100);
    if (!stL) return;
    __half* o = (__half*)out + blockIdx.y * planeH;

    float4 bb0 = make_float4(0.f, 0.f, 0.f, 0.f), bb1 = bb0;
    if (EPI == 1) {
        bb0 = *(const float4*)&db[col_off + c0];
        if (stH) bb1 = *(const float4*)&db[col_off + c0 + 4];
    }
#pragma unroll
    for (int r = 0; r < TM; ++r) {
        int n = n0 + ty * TM + r;
        float4 L = accL[r], H4 = accH[r];
        if (EPI == 0) {
            float d = db[n];
            L.x *= d; L.y *= d; L.z *= d; L.w *= d;
            H4.x *= d; H4.y *= d; H4.z *= d; H4.w *= d;
        } else {
            L.x = fmaxf(L.x + bb0.x, 0.f); L.y = fmaxf(L.y + bb0.y, 0.f);
            L.z = fmaxf(L.z + bb0.z, 0.f); L.w = fmaxf(L.w + bb0.w, 0.f);
            H4.x = fmaxf(H4.x + bb1.x, 0.f); H4.y = fmaxf(H4.y + bb1.y, 0.f);
            H4.z = fmaxf(H4.z + bb1.z, 0.f); H4.w = fmaxf(H4.w + bb1.w, 0.f);
        }
        __half2 p[4];
        p[0] = __float22half2_rn(make_float2(L.x, L.y));
        p[1] = __float22half2_rn(make_float2(L.z, L.w));
        p[2] = __float22half2_rn(make_float2(H4.x, H4.y));
        p[3] = __float22half2_rn(make_float2(H4.z, H4.w));
        size_t off = (size_t)n * 104 + c0;
        if (stH) *(uint4*)&o[off] = *(uint4*)p;       // 8 halves, 16B-aligned
        else     *(uint2*)&o[off] = *(uint2*)p;       // tx==12: 4 halves, 8B-aligned
    }
}

// ---------------- Aggregation over fp16 rows (pitch 52 half2, one wave per node) ----
// acc[n] = Y[n] + sum_{src in in(n)} Y[src]   (f32 accumulate)
// L1=true : h1s[n] = (half) relu(dis[n]*acc + b) * dis[n]
// L1=false: g2[n]  = (float) dis[n]*acc

template <bool L1>
__global__ void agg_h_kernel(const __half2* __restrict__ Y, const int* __restrict__ offs,
                             const int* __restrict__ csr, const float* __restrict__ dis,
                             const float* __restrict__ bias, void* __restrict__ out,
                             int n_nodes) {
    int wave = threadIdx.x >> 6, lane = threadIdx.x & 63;
    int n = blockIdx.x * 4 + wave;
    if (n >= n_nodes) return;
    bool act = lane < 50;
    float ax = 0.f, ay = 0.f;
    if (act) {
        float2 v = __half22float2(Y[(size_t)n * 52 + lane]);  // self-loop term
        ax = v.x; ay = v.y;
    }
    int e0 = offs[n], e1 = offs[n + 1];
    for (int eb = e0; eb < e1; eb += 64) {
        int cdeg = min(e1 - eb, 64);
        int my = (lane < cdeg) ? csr[eb + lane] : 0;  // coalesced batch of edge srcs
        int i = 0;
        for (; i + 4 <= cdeg; i += 4) {
            int s0 = __shfl(my, i), s1 = __shfl(my, i + 1);
            int s2 = __shfl(my, i + 2), s3 = __shfl(my, i + 3);
            if (act) {
                float2 v0 = __half22float2(Y[(size_t)s0 * 52 + lane]);
                float2 v1 = __half22float2(Y[(size_t)s1 * 52 + lane]);
                float2 v2 = __half22float2(Y[(size_t)s2 * 52 + lane]);
                float2 v3 = __half22float2(Y[(size_t)s3 * 52 + lane]);
                ax += (v0.x + v1.x) + (v2.x + v3.x);
                ay += (v0.y + v1.y) + (v2.y + v3.y);
            }
        }
        for (; i < cdeg; ++i) {
            int s = __shfl(my, i);
            if (act) {
                float2 v = __half22float2(Y[(size_t)s * 52 + lane]);
                ax += v.x; ay += v.y;
            }
        }
    }
    if (act) {
        float d = dis[n];
        if (L1) {
            int f = lane * 2;
            float ox = fmaxf(fmaf(ax, d, bias[f]), 0.f) * d;
            float oy = fmaxf(fmaf(ay, d, bias[f + 1]), 0.f) * d;
            ((__half2*)out)[(size_t)n * 52 + lane] = __float22half2_rn(make_float2(ox, oy));
        } else {
            ((float2*)out)[(size_t)n * 50 + lane] = make_float2(ax * d, ay * d);
        }
    }
}

// ---------------- Final FC from fp16 h2 col-planes ----------------
// out[n][c] = sum_p sum_k h2[p][n][k] * Wfc[p*100+k][c] + bfc[c]

__global__ void fc_h_kernel(const __half2* __restrict__ h2, size_t plane2,
                            const float* __restrict__ W, const float* __restrict__ b,
                            float* __restrict__ out, int n_rows) {
    int idx = blockIdx.x * blockDim.x + threadIdx.x;
    int n = idx >> 2;
    int cg = (idx & 3) * 4;
    if (n >= n_rows) return;
    float a0 = 0.f, a1 = 0.f, a2 = 0.f, a3 = 0.f;
#pragma unroll
    for (int p = 0; p < 2; ++p) {
        const __half2* hr = h2 + p * plane2 + (size_t)n * 52;
        const float* Wp = W + (size_t)(p * 100) * F_OUT + cg;
#pragma unroll 5
        for (int k2 = 0; k2 < 50; ++k2) {
            float2 hv = __half22float2(hr[k2]);
            float4 w0 = *(const float4*)&Wp[(2 * k2) * F_OUT];
            float4 w1 = *(const float4*)&Wp[(2 * k2 + 1) * F_OUT];
            a0 = fmaf(hv.x, w0.x, fmaf(hv.y, w1.x, a0));
            a1 = fmaf(hv.x, w0.y, fmaf(hv.y, w1.y, a1));
            a2 = fmaf(hv.x, w0.z, fmaf(hv.y, w1.z, a2));
            a3 = fmaf(hv.x, w0.w, fmaf(hv.y, w1.w, a3));
        }
    }
    float4 bv = *(const float4*)&b[cg];
    float4 o = {a0 + bv.x, a1 + bv.y, a2 + bv.z, a3 + bv.w};
    *(float4*)&out[(size_t)n * F_OUT + cg] = o;
}

// ---------------- Launch ----------------

extern "C" void kernel_launch(void* const* d_in, const int* in_sizes, int n_in,
                              void* d_out, int out_size, void* d_ws, size_t ws_size,
                              hipStream_t stream) {
    const float* x   = (const float*)d_in[0];
    const int*   ei  = (const int*)d_in[1];
    const float* W1  = (const float*)d_in[2];
    const float* b1  = (const float*)d_in[3];
    const float* W2  = (const float*)d_in[4];
    const float* b2  = (const float*)d_in[5];
    const float* Wfc = (const float*)d_in[6];
    const float* bfc = (const float*)d_in[7];
    float* out = (float*)d_out;

    const int N = N_NODES, E = N_EDGES;
    const int* row = ei;
    const int* col = ei + E;
    const int N4 = N / 4;            // 12500 int4s
    const int NB = (N4 + 1023) / 1024;  // 13 scan blocks

    // Workspace layout (all sections 16B-aligned); total ~45 MB
    char* ws = (char*)d_ws;
    int*    cnt    = (int*)ws;      ws += (size_t)N * 4;
    int*    cursor = (int*)ws;      ws += (size_t)N * 4;
    float*  dis    = (float*)ws;    ws += (size_t)N * 4;
    int*    offs   = (int*)ws;      ws += (size_t)(N + 4) * 4;
    int*    csr    = (int*)ws;      ws += (size_t)E * 4;
    int*    bsum   = (int*)ws;      ws += 64;
    int*    bbase  = (int*)ws;      ws += 64;
    __half* y1s    = (__half*)ws;   ws += (size_t)N * 104 * 2;  // 10.4 MB, pitch 104
    __half* h1s    = (__half*)ws;   ws += (size_t)N * 104 * 2;  // 10.4 MB
    float*  g2     = (float*)ws;    ws += (size_t)N * H1 * 4;   // 20 MB
    __half* h2     = y1s;  // overlay: y1s+h1s (20.8 MB) dead before gemm2; h2 = 2 planes x 10.4 MB

    hipMemsetAsync(cnt, 0, (size_t)N * 2 * 4, stream);  // cnt + cursor (contiguous)

    count_kernel<<<(E + 255) / 256, 256, 0, stream>>>(col, cnt, E);
    dis_kernel<<<(N + 255) / 256, 256, 0, stream>>>(cnt, dis, N);
    scan_block_kernel<<<NB, 1024, 0, stream>>>(cnt, offs, bsum, N4);
    scan_bsum_kernel<<<1, 64, 0, stream>>>(bsum, bbase, NB);
    scan_add_kernel<<<(N4 + 255) / 256, 256, 0, stream>>>(offs, bbase, N4, N, NB);
    fill_kernel<<<(E + 255) / 256, 256, 0, stream>>>(row, col, offs, cursor, csr, E);

    // Layer 1: y1s = fp16((x@W1)*dis) ; h1s = fp16(relu(dis*agg(y1s) + b1) * dis)
    gemm_tiled_kernel<F_IN, 32, H1, 0><<<dim3(N / 80, 1), 256, 0, stream>>>(x, W1, dis, y1s, 0);
    agg_h_kernel<true><<<N / 4, 256, 0, stream>>>((const __half2*)y1s, offs, csr, dis, b1, h1s, N);

    // Layer 2: g2 = f32(dis*agg(h1s)) ; h2 = fp16(relu(g2@W2 + b2)) in 2 col-planes
    agg_h_kernel<false><<<N / 4, 256, 0, stream>>>((const __half2*)h1s, offs, csr, dis, nullptr, g2, N);
    gemm_tiled_kernel<H1, 20, H2, 1><<<dim3(N / 80, 2), 256, 0, stream>>>(g2, W2, b2, h2, (size_t)N * 104);

    // out = h2 @ Wfc + bfc
    fc_h_kernel<<<(N * 4 + 255) / 256, 256, 0, stream>>>((const __half2*)h2, (size_t)N * 52, Wfc, bfc, out, N);
}